// Round 1
// baseline (774.826 us; speedup 1.0000x reference)
//
#include <hip/hip_runtime.h>

#define CRF_B 256
#define CRF_L 1024
#define CRF_T 64

// One wave (64 lanes) per chain. Chains: blockIdx < 256 -> forward pass for
// batch b=blockIdx; blockIdx >= 256 -> backward pass for batch b=blockIdx-256.
// Lane = tag index k. E = exp(trans) held in 64 per-lane registers
// (column k for fwd, row k for bwd). Per-step: rebase by state[lane0],
// exp -> LDS broadcast -> 16x ds_read_b128 + 64 FMA -> log -> +em.
__global__ __launch_bounds__(64)
void crf_scan_kernel(const float* __restrict__ em,
                     const float* __restrict__ start_t,
                     const float* __restrict__ end_t,
                     const float* __restrict__ trans,
                     const int* __restrict__ mask,
                     float* __restrict__ alpha,   // ws: (L,B,T)
                     float* __restrict__ beta,    // d_out: (L,B,T)
                     float* __restrict__ zbuf)    // ws tail: (B)
{
    const int lane = threadIdx.x;
    const int c = blockIdx.x;
    const bool is_fwd = (c < CRF_B);
    const int b = is_fwd ? c : c - CRF_B;

    __shared__ float shp[2][CRF_T];   // double-buffered p broadcast

    // E in registers: fwd lane k holds E[j][k] (column), bwd holds E[k][j] (row).
    float e[CRF_T];
    if (is_fwd) {
#pragma unroll
        for (int j = 0; j < CRF_T; ++j)
            e[j] = __expf(trans[j * CRF_T + lane]);
    } else {
#pragma unroll
        for (int j = 0; j < CRF_T; ++j)
            e[j] = __expf(trans[lane * CRF_T + j]);
    }

    const float* emb = em + (size_t)b * CRF_L * CRF_T;
    const int*   mb  = mask + (size_t)b * CRF_L;

    if (is_fwd) {
        float state = emb[lane] + start_t[lane];
        alpha[(size_t)b * CRF_T + lane] = state;            // t=0
        // depth-4 prefetch pipeline (named regs -> stays in VGPRs)
        float pe0 = emb[(size_t)1 * CRF_T + lane];
        float pe1 = emb[(size_t)2 * CRF_T + lane];
        float pe2 = emb[(size_t)3 * CRF_T + lane];
        float pe3 = emb[(size_t)4 * CRF_T + lane];
        int pm0 = mb[1], pm1 = mb[2], pm2 = mb[3], pm3 = mb[4];
        for (int t = 1; t < CRF_L; ++t) {
            float emv = pe0; int mv = pm0;
            pe0 = pe1; pe1 = pe2; pe2 = pe3;
            pm0 = pm1; pm1 = pm2; pm2 = pm3;
            int tn = t + 4; if (tn > CRF_L - 1) tn = CRF_L - 1;
            pe3 = emb[(size_t)tn * CRF_T + lane];
            pm3 = mb[tn];

            float shift = __shfl(state, 0);
            int buf = t & 1;
            shp[buf][lane] = __expf(state - shift);
            __syncthreads();
            const float4* p4 = (const float4*)shp[buf];
            float a0 = 0.f, a1 = 0.f, a2 = 0.f, a3 = 0.f;
#pragma unroll
            for (int j4 = 0; j4 < 16; ++j4) {
                float4 p = p4[j4];
                a0 = fmaf(p.x, e[j4 * 4 + 0], a0);
                a1 = fmaf(p.y, e[j4 * 4 + 1], a1);
                a2 = fmaf(p.z, e[j4 * 4 + 2], a2);
                a3 = fmaf(p.w, e[j4 * 4 + 3], a3);
            }
            float nv = shift + __logf((a0 + a1) + (a2 + a3)) + emv;
            state = (mv != 0) ? nv : state;
            alpha[((size_t)t * CRF_B + b) * CRF_T + lane] = state;
        }
        // z_b = lse_k(alpha[L-1][k] + end[k])
        float v = state + end_t[lane];
        float m = v;
        for (int off = 32; off; off >>= 1) m = fmaxf(m, __shfl_xor(m, off));
        float s = __expf(v - m);
        for (int off = 32; off; off >>= 1) s += __shfl_xor(s, off);
        if (lane == 0) zbuf[b] = m + __logf(s);
    } else {
        float state = end_t[lane];
        beta[((size_t)(CRF_L - 1) * CRF_B + b) * CRF_T + lane] = state;
        float pe0 = emb[(size_t)(CRF_L - 1) * CRF_T + lane];
        float pe1 = emb[(size_t)(CRF_L - 2) * CRF_T + lane];
        float pe2 = emb[(size_t)(CRF_L - 3) * CRF_T + lane];
        float pe3 = emb[(size_t)(CRF_L - 4) * CRF_T + lane];
        int pm0 = mb[CRF_L - 1], pm1 = mb[CRF_L - 2],
            pm2 = mb[CRF_L - 3], pm3 = mb[CRF_L - 4];
        for (int i = CRF_L - 1; i >= 1; --i) {
            float emv = pe0; int mv = pm0;
            pe0 = pe1; pe1 = pe2; pe2 = pe3;
            pm0 = pm1; pm1 = pm2; pm2 = pm3;
            int tn = i - 4; if (tn < 1) tn = 1;
            pe3 = emb[(size_t)tn * CRF_T + lane];
            pm3 = mb[tn];

            // beta[i-1][k] = lse_j(beta[i][j] + em[i][j] + trans[k][j])
            float u = state + emv;
            float shift = __shfl(u, 0);
            int buf = i & 1;
            shp[buf][lane] = __expf(u - shift);
            __syncthreads();
            const float4* p4 = (const float4*)shp[buf];
            float a0 = 0.f, a1 = 0.f, a2 = 0.f, a3 = 0.f;
#pragma unroll
            for (int j4 = 0; j4 < 16; ++j4) {
                float4 p = p4[j4];
                a0 = fmaf(p.x, e[j4 * 4 + 0], a0);
                a1 = fmaf(p.y, e[j4 * 4 + 1], a1);
                a2 = fmaf(p.z, e[j4 * 4 + 2], a2);
                a3 = fmaf(p.w, e[j4 * 4 + 3], a3);
            }
            float nv = shift + __logf((a0 + a1) + (a2 + a3));
            state = (mv != 0) ? nv : state;
            beta[((size_t)(i - 1) * CRF_B + b) * CRF_T + lane] = state;
        }
    }
}

// out = exp(alpha + beta - z[b]); beta already sits in d_out (in-place RMW).
__global__ __launch_bounds__(256)
void crf_finalize_kernel(const float* __restrict__ alpha,
                         const float* __restrict__ zbuf,
                         float* __restrict__ out)
{
    size_t i4 = (size_t)blockIdx.x * blockDim.x + threadIdx.x;
    const float4* a4 = (const float4*)alpha;
    float4* o4 = (float4*)out;
    int b = (int)((i4 >> 4) & (CRF_B - 1));   // 16 float4 per (t,b) row
    float z = zbuf[b];
    float4 a = a4[i4];
    float4 bb = o4[i4];
    float4 o;
    o.x = __expf(a.x + bb.x - z);
    o.y = __expf(a.y + bb.y - z);
    o.z = __expf(a.z + bb.z - z);
    o.w = __expf(a.w + bb.w - z);
    o4[i4] = o;
}

extern "C" void kernel_launch(void* const* d_in, const int* in_sizes, int n_in,
                              void* d_out, int out_size, void* d_ws, size_t ws_size,
                              hipStream_t stream) {
    const float* em = (const float*)d_in[0];
    const float* st = (const float*)d_in[1];
    const float* en = (const float*)d_in[2];
    const float* tr = (const float*)d_in[3];
    const int*   mk = (const int*)d_in[4];
    float* out   = (float*)d_out;
    float* alpha = (float*)d_ws;
    float* zbuf  = alpha + (size_t)CRF_L * CRF_B * CRF_T;

    crf_scan_kernel<<<2 * CRF_B, CRF_T, 0, stream>>>(em, st, en, tr, mk,
                                                     alpha, out, zbuf);
    size_t n4 = (size_t)CRF_L * CRF_B * CRF_T / 4;
    crf_finalize_kernel<<<(int)(n4 / 256), 256, 0, stream>>>(alpha, zbuf, out);
}

// Round 2
// 631.433 us; speedup vs baseline: 1.2271x; 1.2271x over previous
//
#include <hip/hip_runtime.h>

#define B_ 256
#define L_ 1024
#define T_ 64

typedef float f4v __attribute__((ext_vector_type(4)));

__device__ __forceinline__ float rfl(float x) {
    return __int_as_float(__builtin_amdgcn_readfirstlane(__float_as_int(x)));
}

// One wave per chain; blockIdx<256: forward for batch b; else backward.
// Lane = tag k. E=exp(trans) in 64 VGPRs (col k fwd, row k bwd).
// State in exp domain: true log-state = c + log(u). Per step:
//   write u (fwd) / u*exp(em) (bwd) to LDS, broadcast-read, 64 FMA dot,
//   scale by r=1/u[0] (side chain), mask-select, store c+log(u') (side chain).
// No s_barrier: single-wave block, same-wave DS ops are in-order (RAW safe);
// wave_barrier() is a zero-cost compiler scheduling fence.
__global__ __launch_bounds__(64)
void crf_scan(const float* __restrict__ em, const float* __restrict__ start_t,
              const float* __restrict__ end_t, const float* __restrict__ trans,
              const int* __restrict__ mask, float* __restrict__ alpha,
              float* __restrict__ beta, float* __restrict__ zbuf)
{
    const int lane = threadIdx.x;
    const int cb = blockIdx.x;
    const bool fwd = cb < B_;
    const int b = fwd ? cb : cb - B_;

    __shared__ float shu[T_];

    float e[T_];
    if (fwd) {
#pragma unroll
        for (int j = 0; j < T_; ++j) e[j] = __expf(trans[j * T_ + lane]);
    } else {
#pragma unroll
        for (int j = 0; j < T_; ++j) e[j] = __expf(trans[lane * T_ + j]);
    }

    const float* emb = em + (size_t)b * (L_ * T_);
    const int* mb = mask + (size_t)b * L_;
    const size_t stride = (size_t)B_ * T_;

    if (fwd) {
        float st0 = emb[lane] + start_t[lane];
        float c = rfl(st0);
        float u = __expf(st0 - c);                 // u[0] == 1
        float* ap = alpha + (size_t)b * T_ + lane;
        __builtin_nontemporal_store(st0, ap);
        ap += stride;

        // depth-6 em/mask prefetch (named regs)
        float pe0 = emb[1 * T_ + lane], pe1 = emb[2 * T_ + lane],
              pe2 = emb[3 * T_ + lane], pe3 = emb[4 * T_ + lane],
              pe4 = emb[5 * T_ + lane], pe5 = emb[6 * T_ + lane];
        int pm0 = mb[1], pm1 = mb[2], pm2 = mb[3], pm3 = mb[4],
            pm4 = mb[5], pm5 = mb[6];

        for (int t = 1; t < L_; ++t) {
            float f = __expf(pe0);                 // off-chain: data arrived ~6 steps ago
            int mv = pm0;
            pe0 = pe1; pe1 = pe2; pe2 = pe3; pe3 = pe4; pe4 = pe5;
            pm0 = pm1; pm1 = pm2; pm2 = pm3; pm3 = pm4; pm4 = pm5;
            int tn = t + 6; if (tn > L_ - 1) tn = L_ - 1;
            pe5 = emb[tn * T_ + lane];
            pm5 = mb[tn];

            shu[lane] = u;
            __builtin_amdgcn_wave_barrier();
            float u0v = rfl(u);                    // side chain during dot:
            float r = __builtin_amdgcn_rcpf(u0v);  //   1/u[0]
            float um = u * r;                      //   masked-branch value
            float s = f * r;                       //   combined scale
            c = c + __logf(u0v);                   //   scale bookkeeping
            const f4v* q4 = (const f4v*)shu;
            float a0 = 0.f, a1 = 0.f, a2 = 0.f, a3 = 0.f;
#pragma unroll
            for (int j4 = 0; j4 < 16; ++j4) {
                f4v q = q4[j4];
                a0 = fmaf(q.x, e[4 * j4 + 0], a0);
                a1 = fmaf(q.y, e[4 * j4 + 1], a1);
                a2 = fmaf(q.z, e[4 * j4 + 2], a2);
                a3 = fmaf(q.w, e[4 * j4 + 3], a3);
            }
            float cand = ((a0 + a1) + (a2 + a3)) * s;
            float un = (mv != 0) ? cand : um;
            float av = c + __logf(un);             // side chain (store only)
            __builtin_nontemporal_store(av, ap);
            ap += stride;
            u = un;
        }
        // z_b = c + log(sum_k u_k * exp(end_k))
        float v = u * __expf(end_t[lane]);
        for (int off = 32; off; off >>= 1) v += __shfl_xor(v, off);
        if (lane == 0) zbuf[b] = c + __logf(v);
    } else {
        float bv0 = end_t[lane];
        float c = rfl(bv0);
        float u = __expf(bv0 - c);
        float* bp = beta + ((size_t)(L_ - 1) * B_ + b) * T_ + lane;
        __builtin_nontemporal_store(bv0, bp);
        bp -= stride;

        float pe0 = emb[(L_ - 1) * T_ + lane], pe1 = emb[(L_ - 2) * T_ + lane],
              pe2 = emb[(L_ - 3) * T_ + lane], pe3 = emb[(L_ - 4) * T_ + lane],
              pe4 = emb[(L_ - 5) * T_ + lane], pe5 = emb[(L_ - 6) * T_ + lane];
        int pm0 = mb[L_ - 1], pm1 = mb[L_ - 2], pm2 = mb[L_ - 3],
            pm3 = mb[L_ - 4], pm4 = mb[L_ - 5], pm5 = mb[L_ - 6];

        for (int i = L_ - 1; i >= 1; --i) {
            float f = __expf(pe0);
            int mv = pm0;
            pe0 = pe1; pe1 = pe2; pe2 = pe3; pe3 = pe4; pe4 = pe5;
            pm0 = pm1; pm1 = pm2; pm2 = pm3; pm3 = pm4; pm4 = pm5;
            int tn = i - 6; if (tn < 1) tn = 1;
            pe5 = emb[tn * T_ + lane];
            pm5 = mb[tn];

            float w = u * f;                       // em applied on j side
            shu[lane] = w;
            __builtin_amdgcn_wave_barrier();
            float u0v = rfl(u);
            float r = __builtin_amdgcn_rcpf(u0v);
            float um = u * r;
            c = c + __logf(u0v);
            const f4v* q4 = (const f4v*)shu;
            float a0 = 0.f, a1 = 0.f, a2 = 0.f, a3 = 0.f;
#pragma unroll
            for (int j4 = 0; j4 < 16; ++j4) {
                f4v q = q4[j4];
                a0 = fmaf(q.x, e[4 * j4 + 0], a0);
                a1 = fmaf(q.y, e[4 * j4 + 1], a1);
                a2 = fmaf(q.z, e[4 * j4 + 2], a2);
                a3 = fmaf(q.w, e[4 * j4 + 3], a3);
            }
            float cand = ((a0 + a1) + (a2 + a3)) * r;
            float un = (mv != 0) ? cand : um;
            float bvv = c + __logf(un);
            __builtin_nontemporal_store(bvv, bp);
            bp -= stride;
            u = un;
        }
    }
}

// out = exp(alpha + beta - z[b]); beta already resides in d_out.
__global__ __launch_bounds__(256)
void crf_finalize(const float* __restrict__ alpha,
                  const float* __restrict__ zbuf,
                  float* __restrict__ out)
{
    size_t i4 = (size_t)blockIdx.x * blockDim.x + threadIdx.x;
    const f4v* a4 = (const f4v*)alpha;
    f4v* o4 = (f4v*)out;
    int b = (int)((i4 >> 4) & (B_ - 1));           // 16 float4 per (t,b) row
    float z = zbuf[b];
    f4v a = __builtin_nontemporal_load(&a4[i4]);
    f4v bb = __builtin_nontemporal_load(&o4[i4]);
    f4v o;
    o.x = __expf(a.x + bb.x - z);
    o.y = __expf(a.y + bb.y - z);
    o.z = __expf(a.z + bb.z - z);
    o.w = __expf(a.w + bb.w - z);
    __builtin_nontemporal_store(o, &o4[i4]);
}

extern "C" void kernel_launch(void* const* d_in, const int* in_sizes, int n_in,
                              void* d_out, int out_size, void* d_ws, size_t ws_size,
                              hipStream_t stream) {
    const float* em = (const float*)d_in[0];
    const float* st = (const float*)d_in[1];
    const float* en = (const float*)d_in[2];
    const float* tr = (const float*)d_in[3];
    const int*   mk = (const int*)d_in[4];
    float* out   = (float*)d_out;
    float* alpha = (float*)d_ws;
    float* zbuf  = alpha + (size_t)L_ * B_ * T_;

    crf_scan<<<2 * B_, T_, 0, stream>>>(em, st, en, tr, mk, alpha, out, zbuf);
    size_t n4 = (size_t)L_ * B_ * T_ / 4;
    crf_finalize<<<(int)(n4 / 256), 256, 0, stream>>>(alpha, zbuf, out);
}

// Round 3
// 518.281 us; speedup vs baseline: 1.4950x; 1.2183x over previous
//
#include <hip/hip_runtime.h>

#define B_ 256
#define L_ 1024
#define T_ 64

typedef float f4v __attribute__((ext_vector_type(4)));
typedef float f2v __attribute__((ext_vector_type(2)));

__device__ __forceinline__ float rfl(float x) {
    return __int_as_float(__builtin_amdgcn_readfirstlane(__float_as_int(x)));
}

// packed fp32 FMA: d = a*b + c on both halves (full-rate on CDNA)
__device__ __forceinline__ f2v pkfma(f2v a, f2v b, f2v c) {
    f2v d;
    asm("v_pk_fma_f32 %0, %1, %2, %3" : "=v"(d) : "v"(a), "v"(b), "v"(c));
    return d;
}

// One wave per chain; blockIdx<256: forward for batch b; else backward.
// Lane = tag k. E=exp(trans) as 32 packed f2 regs (col k fwd, row k bwd).
// State in exp domain: true log-state = c + log(u), u[0]==1 invariant.
// Per step: ds_write u -> 16 batched ds_read_b128 -> 32 v_pk_fma_f32 dot
// -> scale by r=1/u[0] (side chain) -> mask select -> store c+log(u').
// No s_barrier (single-wave block; same-wave DS ops are in-order).
__global__ __launch_bounds__(64, 1)
void crf_scan(const float* __restrict__ em, const float* __restrict__ start_t,
              const float* __restrict__ end_t, const float* __restrict__ trans,
              const int* __restrict__ mask, float* __restrict__ alpha,
              float* __restrict__ beta, float* __restrict__ zbuf)
{
    const int lane = threadIdx.x;
    const int cb = blockIdx.x;
    const bool fwd = cb < B_;
    const int b = fwd ? cb : cb - B_;

    __shared__ float shu[T_];

    f2v e2[32];
    if (fwd) {
#pragma unroll
        for (int j = 0; j < 32; ++j) {
            e2[j].x = __expf(trans[(2 * j + 0) * T_ + lane]);
            e2[j].y = __expf(trans[(2 * j + 1) * T_ + lane]);
        }
    } else {
#pragma unroll
        for (int j = 0; j < 32; ++j) {
            e2[j].x = __expf(trans[lane * T_ + 2 * j + 0]);
            e2[j].y = __expf(trans[lane * T_ + 2 * j + 1]);
        }
    }

    const float* emb = em + (size_t)b * (L_ * T_);
    const int* mb = mask + (size_t)b * L_;
    const size_t stride = (size_t)B_ * T_;

    if (fwd) {
        float st0 = emb[lane] + start_t[lane];
        float c = rfl(st0);
        float u = __expf(st0 - c);                 // u[0] == 1
        float* ap = alpha + (size_t)b * T_ + lane;
        __builtin_nontemporal_store(st0, ap);
        ap += stride;

        float pe0 = emb[1 * T_ + lane], pe1 = emb[2 * T_ + lane],
              pe2 = emb[3 * T_ + lane], pe3 = emb[4 * T_ + lane],
              pe4 = emb[5 * T_ + lane], pe5 = emb[6 * T_ + lane];
        int pm0 = mb[1], pm1 = mb[2], pm2 = mb[3], pm3 = mb[4],
            pm4 = mb[5], pm5 = mb[6];

        for (int t = 1; t < L_; ++t) {
            float f = __expf(pe0);
            int mv = pm0;
            pe0 = pe1; pe1 = pe2; pe2 = pe3; pe3 = pe4; pe4 = pe5;
            pm0 = pm1; pm1 = pm2; pm2 = pm3; pm3 = pm4; pm4 = pm5;
            int tn = t + 6; if (tn > L_ - 1) tn = L_ - 1;
            pe5 = emb[tn * T_ + lane];
            pm5 = mb[tn];

            shu[lane] = u;
            __builtin_amdgcn_wave_barrier();
            float u0v = rfl(u);
            float r = __builtin_amdgcn_rcpf(u0v);
            float um = u * r;
            float s = f * r;
            c = c + __logf(u0v);

            // batched LDS reads (static indices -> stays in VGPRs)
            const f4v* q4 = (const f4v*)shu;
            f4v q[16];
#pragma unroll
            for (int i = 0; i < 16; ++i) q[i] = q4[i];

            f2v aA0 = {0.f,0.f}, aA1 = {0.f,0.f}, aA2 = {0.f,0.f}, aA3 = {0.f,0.f};
            f2v aB0 = {0.f,0.f}, aB1 = {0.f,0.f}, aB2 = {0.f,0.f}, aB3 = {0.f,0.f};
#pragma unroll
            for (int i = 0; i < 16; i += 4) {
                f2v lo0 = {q[i+0].x, q[i+0].y}, hi0 = {q[i+0].z, q[i+0].w};
                f2v lo1 = {q[i+1].x, q[i+1].y}, hi1 = {q[i+1].z, q[i+1].w};
                f2v lo2 = {q[i+2].x, q[i+2].y}, hi2 = {q[i+2].z, q[i+2].w};
                f2v lo3 = {q[i+3].x, q[i+3].y}, hi3 = {q[i+3].z, q[i+3].w};
                aA0 = pkfma(lo0, e2[2*(i+0)],   aA0);
                aB0 = pkfma(hi0, e2[2*(i+0)+1], aB0);
                aA1 = pkfma(lo1, e2[2*(i+1)],   aA1);
                aB1 = pkfma(hi1, e2[2*(i+1)+1], aB1);
                aA2 = pkfma(lo2, e2[2*(i+2)],   aA2);
                aB2 = pkfma(hi2, e2[2*(i+2)+1], aB2);
                aA3 = pkfma(lo3, e2[2*(i+3)],   aA3);
                aB3 = pkfma(hi3, e2[2*(i+3)+1], aB3);
            }
            f2v sT = ((aA0 + aA1) + (aA2 + aA3)) + ((aB0 + aB1) + (aB2 + aB3));
            float dot = sT.x + sT.y;

            float cand = dot * s;
            float un = (mv != 0) ? cand : um;
            float av = c + __logf(un);
            __builtin_nontemporal_store(av, ap);
            ap += stride;
            u = un;
        }
        float v = u * __expf(end_t[lane]);
        for (int off = 32; off; off >>= 1) v += __shfl_xor(v, off);
        if (lane == 0) zbuf[b] = c + __logf(v);
    } else {
        float bv0 = end_t[lane];
        float c = rfl(bv0);
        float u = __expf(bv0 - c);
        float* bp = beta + ((size_t)(L_ - 1) * B_ + b) * T_ + lane;
        __builtin_nontemporal_store(bv0, bp);
        bp -= stride;

        float pe0 = emb[(L_ - 1) * T_ + lane], pe1 = emb[(L_ - 2) * T_ + lane],
              pe2 = emb[(L_ - 3) * T_ + lane], pe3 = emb[(L_ - 4) * T_ + lane],
              pe4 = emb[(L_ - 5) * T_ + lane], pe5 = emb[(L_ - 6) * T_ + lane];
        int pm0 = mb[L_ - 1], pm1 = mb[L_ - 2], pm2 = mb[L_ - 3],
            pm3 = mb[L_ - 4], pm4 = mb[L_ - 5], pm5 = mb[L_ - 6];

        for (int i = L_ - 1; i >= 1; --i) {
            float f = __expf(pe0);
            int mv = pm0;
            pe0 = pe1; pe1 = pe2; pe2 = pe3; pe3 = pe4; pe4 = pe5;
            pm0 = pm1; pm1 = pm2; pm2 = pm3; pm3 = pm4; pm4 = pm5;
            int tn = i - 6; if (tn < 1) tn = 1;
            pe5 = emb[tn * T_ + lane];
            pm5 = mb[tn];

            float w = u * f;                       // em applied on j side
            shu[lane] = w;
            __builtin_amdgcn_wave_barrier();
            float u0v = rfl(u);
            float r = __builtin_amdgcn_rcpf(u0v);
            float um = u * r;
            c = c + __logf(u0v);

            const f4v* q4 = (const f4v*)shu;
            f4v q[16];
#pragma unroll
            for (int i2 = 0; i2 < 16; ++i2) q[i2] = q4[i2];

            f2v aA0 = {0.f,0.f}, aA1 = {0.f,0.f}, aA2 = {0.f,0.f}, aA3 = {0.f,0.f};
            f2v aB0 = {0.f,0.f}, aB1 = {0.f,0.f}, aB2 = {0.f,0.f}, aB3 = {0.f,0.f};
#pragma unroll
            for (int i2 = 0; i2 < 16; i2 += 4) {
                f2v lo0 = {q[i2+0].x, q[i2+0].y}, hi0 = {q[i2+0].z, q[i2+0].w};
                f2v lo1 = {q[i2+1].x, q[i2+1].y}, hi1 = {q[i2+1].z, q[i2+1].w};
                f2v lo2 = {q[i2+2].x, q[i2+2].y}, hi2 = {q[i2+2].z, q[i2+2].w};
                f2v lo3 = {q[i2+3].x, q[i2+3].y}, hi3 = {q[i2+3].z, q[i2+3].w};
                aA0 = pkfma(lo0, e2[2*(i2+0)],   aA0);
                aB0 = pkfma(hi0, e2[2*(i2+0)+1], aB0);
                aA1 = pkfma(lo1, e2[2*(i2+1)],   aA1);
                aB1 = pkfma(hi1, e2[2*(i2+1)+1], aB1);
                aA2 = pkfma(lo2, e2[2*(i2+2)],   aA2);
                aB2 = pkfma(hi2, e2[2*(i2+2)+1], aB2);
                aA3 = pkfma(lo3, e2[2*(i2+3)],   aA3);
                aB3 = pkfma(hi3, e2[2*(i2+3)+1], aB3);
            }
            f2v sT = ((aA0 + aA1) + (aA2 + aA3)) + ((aB0 + aB1) + (aB2 + aB3));
            float dot = sT.x + sT.y;

            float cand = dot * r;
            float un = (mv != 0) ? cand : um;
            float bvv = c + __logf(un);
            __builtin_nontemporal_store(bvv, bp);
            bp -= stride;
            u = un;
        }
    }
}

// out = exp(alpha + beta - z[b]); beta already resides in d_out.
__global__ __launch_bounds__(256)
void crf_finalize(const float* __restrict__ alpha,
                  const float* __restrict__ zbuf,
                  float* __restrict__ out)
{
    size_t i4 = (size_t)blockIdx.x * blockDim.x + threadIdx.x;
    const f4v* a4 = (const f4v*)alpha;
    f4v* o4 = (f4v*)out;
    int b = (int)((i4 >> 4) & (B_ - 1));           // 16 float4 per (t,b) row
    float z = zbuf[b];
    f4v a = __builtin_nontemporal_load(&a4[i4]);
    f4v bb = __builtin_nontemporal_load(&o4[i4]);
    f4v o;
    o.x = __expf(a.x + bb.x - z);
    o.y = __expf(a.y + bb.y - z);
    o.z = __expf(a.z + bb.z - z);
    o.w = __expf(a.w + bb.w - z);
    __builtin_nontemporal_store(o, &o4[i4]);
}

extern "C" void kernel_launch(void* const* d_in, const int* in_sizes, int n_in,
                              void* d_out, int out_size, void* d_ws, size_t ws_size,
                              hipStream_t stream) {
    const float* em = (const float*)d_in[0];
    const float* st = (const float*)d_in[1];
    const float* en = (const float*)d_in[2];
    const float* tr = (const float*)d_in[3];
    const int*   mk = (const int*)d_in[4];
    float* out   = (float*)d_out;
    float* alpha = (float*)d_ws;
    float* zbuf  = alpha + (size_t)L_ * B_ * T_;

    crf_scan<<<2 * B_, T_, 0, stream>>>(em, st, en, tr, mk, alpha, out, zbuf);
    size_t n4 = (size_t)L_ * B_ * T_ / 4;
    crf_finalize<<<(int)(n4 / 256), 256, 0, stream>>>(alpha, zbuf, out);
}